// Round 1
// baseline (861.268 us; speedup 1.0000x reference)
//
#include <hip/hip_runtime.h>
#include <math.h>

// Problem constants
#define SEQ 384
#define HDIM 768
#define NHEAD 12
#define DHEAD 64

// ---------------------------------------------------------------------------
// Kernel A: fused QKV projection.  C = X @ W + b for W in {Wq,Wk,Wv}
// X: (384,768) row-major, W: (768,768) row-major, C: (384,768)
// grid (6 mtiles, 12 ntiles, 3 matrices), block 256, tile 64x64, ktile 16
// ---------------------------------------------------------------------------
__global__ __launch_bounds__(256)
void qkv_gemm(const float* __restrict__ X,
              const float* __restrict__ Wq, const float* __restrict__ bq,
              const float* __restrict__ Wk, const float* __restrict__ bk,
              const float* __restrict__ Wv, const float* __restrict__ bv,
              float* __restrict__ q, float* __restrict__ k, float* __restrict__ v)
{
    __shared__ float Xs[16][68];   // [k][m], padded
    __shared__ float Ws[16][68];   // [k][n], padded
    const int z = blockIdx.z;
    const float* W    = (z == 0) ? Wq : (z == 1) ? Wk : Wv;
    const float* bias = (z == 0) ? bq : (z == 1) ? bk : bv;
    float* out        = (z == 0) ? q  : (z == 1) ? k  : v;

    const int m0 = blockIdx.x * 64;
    const int n0 = blockIdx.y * 64;
    const int tid = threadIdx.x;
    const int ty = tid / 16, tx = tid % 16;

    const int lxm = tid / 4,  lxk = (tid % 4) * 4;   // X loader: 64 rows x 16 k
    const int lwk = tid / 16, lwn = (tid % 16) * 4;  // W loader: 16 rows x 64 n

    float acc[4][4] = {};

    for (int k0 = 0; k0 < HDIM; k0 += 16) {
        float4 xa = *(const float4*)&X[(m0 + lxm) * HDIM + k0 + lxk];
        float4 wa = *(const float4*)&W[(size_t)(k0 + lwk) * HDIM + n0 + lwn];
        __syncthreads();
        Xs[lxk + 0][lxm] = xa.x; Xs[lxk + 1][lxm] = xa.y;
        Xs[lxk + 2][lxm] = xa.z; Xs[lxk + 3][lxm] = xa.w;
        *(float4*)&Ws[lwk][lwn] = wa;
        __syncthreads();
        #pragma unroll
        for (int kk = 0; kk < 16; kk++) {
            float4 a4 = *(const float4*)&Xs[kk][4 * ty];
            float4 b4 = *(const float4*)&Ws[kk][4 * tx];
            float a[4] = {a4.x, a4.y, a4.z, a4.w};
            float b[4] = {b4.x, b4.y, b4.z, b4.w};
            #pragma unroll
            for (int ia = 0; ia < 4; ia++)
                #pragma unroll
                for (int ib = 0; ib < 4; ib++)
                    acc[ia][ib] = fmaf(a[ia], b[ib], acc[ia][ib]);
        }
    }
    float4 bv4 = *(const float4*)&bias[n0 + 4 * tx];
    #pragma unroll
    for (int ia = 0; ia < 4; ia++) {
        float4 o;
        o.x = acc[ia][0] + bv4.x; o.y = acc[ia][1] + bv4.y;
        o.z = acc[ia][2] + bv4.z; o.w = acc[ia][3] + bv4.w;
        *(float4*)&out[(size_t)(m0 + 4 * ty + ia) * HDIM + n0 + 4 * tx] = o;
    }
}

// ---------------------------------------------------------------------------
// Kernel B: positional projections.
//   qp[i,h,e] = sum_d q[i, h*64+d] * Wpk[e*768 + h*64 + d]
//   kp[j,h,e] = sum_d k[j, h*64+d] * Wpq[e*768 + h*64 + d]
// grid (6 itiles, 12 etiles, 24 = h + 12*s), block 256, tile 64x64, K=64
// output layout: qp[(i*12 + h)*768 + e]
// ---------------------------------------------------------------------------
__global__ __launch_bounds__(256)
void pos_proj(const float* __restrict__ q, const float* __restrict__ k,
              const float* __restrict__ Wpk, const float* __restrict__ Wpq,
              float* __restrict__ qp, float* __restrict__ kp)
{
    __shared__ float As[64][68];   // [d][i]
    __shared__ float Bs[64][68];   // [d][e]
    const int h = blockIdx.z % NHEAD;
    const int s = blockIdx.z / NHEAD;
    const float* Asrc = s ? k   : q;
    const float* Wsrc = s ? Wpq : Wpk;
    float* out        = s ? kp  : qp;

    const int i0 = blockIdx.x * 64, e0 = blockIdx.y * 64;
    const int tid = threadIdx.x;
    const int dg = tid % 16, row = tid / 16;   // 16 float4 per row, 16 rows/round

    #pragma unroll
    for (int r = 0; r < 4; r++) {
        const int rr = r * 16 + row;
        float4 a4 = *(const float4*)&Asrc[(size_t)(i0 + rr) * HDIM + h * 64 + dg * 4];
        float4 b4 = *(const float4*)&Wsrc[(size_t)(e0 + rr) * HDIM + h * 64 + dg * 4];
        As[dg * 4 + 0][rr - 0] = a4.x; As[dg * 4 + 1][rr] = a4.y;
        As[dg * 4 + 2][rr] = a4.z;     As[dg * 4 + 3][rr] = a4.w;
        Bs[dg * 4 + 0][rr] = b4.x;     Bs[dg * 4 + 1][rr] = b4.y;
        Bs[dg * 4 + 2][rr] = b4.z;     Bs[dg * 4 + 3][rr] = b4.w;
    }
    __syncthreads();

    const int ty = tid / 16, tx = tid % 16;
    float acc[4][4] = {};
    #pragma unroll 4
    for (int d = 0; d < 64; d++) {
        float4 a4 = *(const float4*)&As[d][4 * ty];
        float4 b4 = *(const float4*)&Bs[d][4 * tx];
        float a[4] = {a4.x, a4.y, a4.z, a4.w};
        float b[4] = {b4.x, b4.y, b4.z, b4.w};
        #pragma unroll
        for (int ia = 0; ia < 4; ia++)
            #pragma unroll
            for (int ib = 0; ib < 4; ib++)
                acc[ia][ib] = fmaf(a[ia], b[ib], acc[ia][ib]);
    }
    #pragma unroll
    for (int ia = 0; ia < 4; ia++) {
        float4 o = make_float4(acc[ia][0], acc[ia][1], acc[ia][2], acc[ia][3]);
        *(float4*)&out[((size_t)(i0 + 4 * ty + ia) * NHEAD + h) * HDIM + e0 + 4 * tx] = o;
    }
}

// ---------------------------------------------------------------------------
// Kernel C: single pass over pos_emb (453 MB).
// Block i computes, for all h and j:
//   A1 [h*S*S + i*S + j] = sum_e pos_emb[i,j,e] * qp[i,h,e]   (= c2p[h,i,j])
//   P2T[h*S*S + i*S + j] = sum_e pos_emb[i,j,e] * kp[i,h,e]   (= p2c[h,j,i])
// 192 threads: rg = tid/96 (12 rows of qp or kp), jl = tid%96 (4 j's each).
// e processed in 24 chunks of 32; P chunk transposed into LDS [e][j].
// ---------------------------------------------------------------------------
__global__ __launch_bounds__(192)
void scores_pos(const float* __restrict__ pe, const float* __restrict__ qp,
                const float* __restrict__ kp,
                float* __restrict__ A1, float* __restrict__ P2T)
{
    __shared__ float Ps[32][388];   // [e][j], pad 388 -> b128 aligned, stores 4-way max
    __shared__ float Ws[32][24];    // [e][row], rows 0..11 = qp heads, 12..23 = kp heads
    const int i  = blockIdx.x;
    const int tid = threadIdx.x;
    const int rg = tid / 96;
    const int jl = tid % 96;

    const float* pebase = pe + (size_t)i * SEQ * HDIM;
    const int wr  = tid / 8;        // 0..23
    const int wec = tid % 8;        // 8 float4 = 32 e's
    const float* wsrc = (wr < NHEAD)
        ? (qp + ((size_t)i * NHEAD + wr) * HDIM)
        : (kp + ((size_t)i * NHEAD + (wr - NHEAD)) * HDIM);

    float acc[12][4] = {};

    for (int c = 0; c < 24; c++) {
        const int e0 = c * 32;
        __syncthreads();   // protect LDS from previous iteration's readers
        float4 w4 = *(const float4*)&wsrc[e0 + wec * 4];
        Ws[wec * 4 + 0][wr] = w4.x; Ws[wec * 4 + 1][wr] = w4.y;
        Ws[wec * 4 + 2][wr] = w4.z; Ws[wec * 4 + 3][wr] = w4.w;
        #pragma unroll
        for (int rnd = 0; rnd < 16; rnd++) {
            const int jrow = rnd * 24 + wr;
            float4 p4 = *(const float4*)&pebase[(size_t)jrow * HDIM + e0 + wec * 4];
            Ps[wec * 4 + 0][jrow] = p4.x; Ps[wec * 4 + 1][jrow] = p4.y;
            Ps[wec * 4 + 2][jrow] = p4.z; Ps[wec * 4 + 3][jrow] = p4.w;
        }
        __syncthreads();
        #pragma unroll 2
        for (int ee = 0; ee < 32; ee++) {
            float4 p4 = *(const float4*)&Ps[ee][4 * jl];
            float4 wa = *(const float4*)&Ws[ee][12 * rg + 0];
            float4 wb = *(const float4*)&Ws[ee][12 * rg + 4];
            float4 wc = *(const float4*)&Ws[ee][12 * rg + 8];
            float p[4] = {p4.x, p4.y, p4.z, p4.w};
            float w[12] = {wa.x, wa.y, wa.z, wa.w, wb.x, wb.y, wb.z, wb.w,
                           wc.x, wc.y, wc.z, wc.w};
            #pragma unroll
            for (int r = 0; r < 12; r++)
                #pragma unroll
                for (int u = 0; u < 4; u++)
                    acc[r][u] = fmaf(w[r], p[u], acc[r][u]);
        }
    }
    float* dst = (rg == 0) ? A1 : P2T;
    #pragma unroll
    for (int r = 0; r < 12; r++) {
        float4 o = make_float4(acc[r][0], acc[r][1], acc[r][2], acc[r][3]);
        *(float4*)&dst[((size_t)r * SEQ + i) * SEQ + 4 * jl] = o;
    }
}

// ---------------------------------------------------------------------------
// Kernel D: per-(i,h) block (384 threads, thread = j):
//   scores[j] = (c2c + A1[h,i,j] + P2T[h,j,i] + qb + kb[j]) / 8 + mask[j]
//   softmax over j, then out[i, h*64+d] = sum_j p_j v[j, h*64+d] / sum
// c2c computed inline (k head rows are L2-resident); qb = q_ih . bpk_h
// (softmax-invariant but included for exactness), kb = k_jh . bpq_h.
// ---------------------------------------------------------------------------
__global__ __launch_bounds__(384)
void attn_out(const float* __restrict__ A1, const float* __restrict__ P2T,
              const float* __restrict__ q, const float* __restrict__ k,
              const float* __restrict__ v,
              const float* __restrict__ bpk, const float* __restrict__ bpq,
              const float* __restrict__ mask, float* __restrict__ out)
{
    const int i = blockIdx.x, h = blockIdx.y;
    const int tid = threadIdx.x;   // = j
    __shared__ float q_s[64], bk_s[64], bq_s[64];
    __shared__ float p_s[SEQ];
    __shared__ float redm[6], reds[6], redv[6 * 64];

    if (tid < 64)       q_s[tid]        = q[(size_t)i * HDIM + h * 64 + tid];
    else if (tid < 128) bk_s[tid - 64]  = bpk[h * 64 + tid - 64];
    else if (tid < 192) bq_s[tid - 128] = bpq[h * 64 + tid - 128];
    __syncthreads();

    const float* kr = k + (size_t)tid * HDIM + h * 64;
    float c2c = 0.f, kb = 0.f;
    #pragma unroll
    for (int dd = 0; dd < 16; dd++) {
        float4 k4 = *(const float4*)(kr + 4 * dd);
        c2c = fmaf(q_s[4 * dd + 0], k4.x, c2c);
        c2c = fmaf(q_s[4 * dd + 1], k4.y, c2c);
        c2c = fmaf(q_s[4 * dd + 2], k4.z, c2c);
        c2c = fmaf(q_s[4 * dd + 3], k4.w, c2c);
        kb  = fmaf(bq_s[4 * dd + 0], k4.x, kb);
        kb  = fmaf(bq_s[4 * dd + 1], k4.y, kb);
        kb  = fmaf(bq_s[4 * dd + 2], k4.z, kb);
        kb  = fmaf(bq_s[4 * dd + 3], k4.w, kb);
    }
    float qb = 0.f;
    #pragma unroll 8
    for (int d = 0; d < 64; d++) qb = fmaf(q_s[d], bk_s[d], qb);

    float sc = (A1[((size_t)h * SEQ + i) * SEQ + tid] +
                P2T[((size_t)h * SEQ + tid) * SEQ + i] +
                c2c + kb + qb) * 0.125f + mask[tid];

    const int lane = tid & 63, w = tid >> 6;
    float m = sc;
    #pragma unroll
    for (int o = 32; o; o >>= 1) m = fmaxf(m, __shfl_xor(m, o));
    if (lane == 0) redm[w] = m;
    __syncthreads();
    m = redm[0];
    #pragma unroll
    for (int t = 1; t < 6; t++) m = fmaxf(m, redm[t]);

    float p = __expf(sc - m);
    float sum = p;
    #pragma unroll
    for (int o = 32; o; o >>= 1) sum += __shfl_xor(sum, o);
    if (lane == 0) reds[w] = sum;
    p_s[tid] = p;
    __syncthreads();
    const float SUM = reds[0] + reds[1] + reds[2] + reds[3] + reds[4] + reds[5];

    float accv = 0.f;
    const float* vbase = v + h * 64 + lane;
    const int j0 = w * 64;
    #pragma unroll 8
    for (int jj = 0; jj < 64; jj++)
        accv = fmaf(p_s[j0 + jj], vbase[(size_t)(j0 + jj) * HDIM], accv);
    redv[w * 64 + lane] = accv;
    __syncthreads();
    if (tid < 64) {
        float o = redv[tid] + redv[64 + tid] + redv[128 + tid] +
                  redv[192 + tid] + redv[256 + tid] + redv[320 + tid];
        out[(size_t)i * HDIM + h * 64 + tid] = o / SUM;
    }
}

// ---------------------------------------------------------------------------
extern "C" void kernel_launch(void* const* d_in, const int* in_sizes, int n_in,
                              void* d_out, int out_size, void* d_ws, size_t ws_size,
                              hipStream_t stream)
{
    const float* hs   = (const float*)d_in[0];
    const float* mask = (const float*)d_in[1];
    const float* pe   = (const float*)d_in[2];
    const float* Wq   = (const float*)d_in[3];
    const float* bq   = (const float*)d_in[4];
    const float* Wk   = (const float*)d_in[5];
    const float* bk   = (const float*)d_in[6];
    const float* Wv   = (const float*)d_in[7];
    const float* bv   = (const float*)d_in[8];
    const float* Wpk  = (const float*)d_in[9];
    const float* bpk  = (const float*)d_in[10];
    const float* Wpq  = (const float*)d_in[11];
    const float* bpq  = (const float*)d_in[12];

    float* ws = (float*)d_ws;
    const size_t SZ_QKV = (size_t)SEQ * HDIM;            // 294912
    const size_t SZ_QP  = (size_t)SEQ * NHEAD * HDIM;    // 3538944
    const size_t SZ_SC  = (size_t)NHEAD * SEQ * SEQ;     // 1769472
    float* q   = ws;
    float* k   = q  + SZ_QKV;
    float* v   = k  + SZ_QKV;
    float* qp  = v  + SZ_QKV;
    float* kp  = qp + SZ_QP;
    float* A1  = kp + SZ_QP;
    float* P2T = A1 + SZ_SC;
    // total: 11,501,568 floats = 46.0 MB of d_ws

    qkv_gemm<<<dim3(6, 12, 3), 256, 0, stream>>>(hs, Wq, bq, Wk, bk, Wv, bv, q, k, v);
    pos_proj<<<dim3(6, 12, 24), 256, 0, stream>>>(q, k, Wpk, Wpq, qp, kp);
    scores_pos<<<dim3(SEQ), 192, 0, stream>>>(pe, qp, kp, A1, P2T);
    attn_out<<<dim3(SEQ, NHEAD), 384, 0, stream>>>(A1, P2T, q, k, v, bpk, bpq, mask,
                                                   (float*)d_out);
}

// Round 2
// 858.205 us; speedup vs baseline: 1.0036x; 1.0036x over previous
//
#include <hip/hip_runtime.h>
#include <math.h>

// Problem constants
#define SEQ 384
#define HDIM 768
#define NHEAD 12
#define DHEAD 64

// ---------------------------------------------------------------------------
// Kernel A: fused QKV projection.  C = X @ W + b for W in {Wq,Wk,Wv}
// ---------------------------------------------------------------------------
__global__ __launch_bounds__(256)
void qkv_gemm(const float* __restrict__ X,
              const float* __restrict__ Wq, const float* __restrict__ bq,
              const float* __restrict__ Wk, const float* __restrict__ bk,
              const float* __restrict__ Wv, const float* __restrict__ bv,
              float* __restrict__ q, float* __restrict__ k, float* __restrict__ v)
{
    __shared__ float Xs[16][68];   // [k][m], padded
    __shared__ float Ws[16][68];   // [k][n], padded
    const int z = blockIdx.z;
    const float* W    = (z == 0) ? Wq : (z == 1) ? Wk : Wv;
    const float* bias = (z == 0) ? bq : (z == 1) ? bk : bv;
    float* out        = (z == 0) ? q  : (z == 1) ? k  : v;

    const int m0 = blockIdx.x * 64;
    const int n0 = blockIdx.y * 64;
    const int tid = threadIdx.x;
    const int ty = tid / 16, tx = tid % 16;

    const int lxm = tid / 4,  lxk = (tid % 4) * 4;   // X loader: 64 rows x 16 k
    const int lwk = tid / 16, lwn = (tid % 16) * 4;  // W loader: 16 rows x 64 n

    float acc[4][4] = {};

    for (int k0 = 0; k0 < HDIM; k0 += 16) {
        float4 xa = *(const float4*)&X[(m0 + lxm) * HDIM + k0 + lxk];
        float4 wa = *(const float4*)&W[(size_t)(k0 + lwk) * HDIM + n0 + lwn];
        __syncthreads();
        Xs[lxk + 0][lxm] = xa.x; Xs[lxk + 1][lxm] = xa.y;
        Xs[lxk + 2][lxm] = xa.z; Xs[lxk + 3][lxm] = xa.w;
        *(float4*)&Ws[lwk][lwn] = wa;
        __syncthreads();
        #pragma unroll
        for (int kk = 0; kk < 16; kk++) {
            float4 a4 = *(const float4*)&Xs[kk][4 * ty];
            float4 b4 = *(const float4*)&Ws[kk][4 * tx];
            float a[4] = {a4.x, a4.y, a4.z, a4.w};
            float b[4] = {b4.x, b4.y, b4.z, b4.w};
            #pragma unroll
            for (int ia = 0; ia < 4; ia++)
                #pragma unroll
                for (int ib = 0; ib < 4; ib++)
                    acc[ia][ib] = fmaf(a[ia], b[ib], acc[ia][ib]);
        }
    }
    float4 bv4 = *(const float4*)&bias[n0 + 4 * tx];
    #pragma unroll
    for (int ia = 0; ia < 4; ia++) {
        float4 o;
        o.x = acc[ia][0] + bv4.x; o.y = acc[ia][1] + bv4.y;
        o.z = acc[ia][2] + bv4.z; o.w = acc[ia][3] + bv4.w;
        *(float4*)&out[(size_t)(m0 + 4 * ty + ia) * HDIM + n0 + 4 * tx] = o;
    }
}

// ---------------------------------------------------------------------------
// Kernel B: positional projections.
//   qp[i,h,e] = sum_d q[i, h*64+d] * Wpk[e*768 + h*64 + d]
//   kp[j,h,e] = sum_d k[j, h*64+d] * Wpq[e*768 + h*64 + d]
// output layout: qp[(i*12 + h)*768 + e]
// ---------------------------------------------------------------------------
__global__ __launch_bounds__(256)
void pos_proj(const float* __restrict__ q, const float* __restrict__ k,
              const float* __restrict__ Wpk, const float* __restrict__ Wpq,
              float* __restrict__ qp, float* __restrict__ kp)
{
    __shared__ float As[64][68];   // [d][i]
    __shared__ float Bs[64][68];   // [d][e]
    const int h = blockIdx.z % NHEAD;
    const int s = blockIdx.z / NHEAD;
    const float* Asrc = s ? k   : q;
    const float* Wsrc = s ? Wpq : Wpk;
    float* out        = s ? kp  : qp;

    const int i0 = blockIdx.x * 64, e0 = blockIdx.y * 64;
    const int tid = threadIdx.x;
    const int dg = tid % 16, row = tid / 16;

    #pragma unroll
    for (int r = 0; r < 4; r++) {
        const int rr = r * 16 + row;
        float4 a4 = *(const float4*)&Asrc[(size_t)(i0 + rr) * HDIM + h * 64 + dg * 4];
        float4 b4 = *(const float4*)&Wsrc[(size_t)(e0 + rr) * HDIM + h * 64 + dg * 4];
        As[dg * 4 + 0][rr] = a4.x; As[dg * 4 + 1][rr] = a4.y;
        As[dg * 4 + 2][rr] = a4.z; As[dg * 4 + 3][rr] = a4.w;
        Bs[dg * 4 + 0][rr] = b4.x; Bs[dg * 4 + 1][rr] = b4.y;
        Bs[dg * 4 + 2][rr] = b4.z; Bs[dg * 4 + 3][rr] = b4.w;
    }
    __syncthreads();

    const int ty = tid / 16, tx = tid % 16;
    float acc[4][4] = {};
    #pragma unroll 4
    for (int d = 0; d < 64; d++) {
        float4 a4 = *(const float4*)&As[d][4 * ty];
        float4 b4 = *(const float4*)&Bs[d][4 * tx];
        float a[4] = {a4.x, a4.y, a4.z, a4.w};
        float b[4] = {b4.x, b4.y, b4.z, b4.w};
        #pragma unroll
        for (int ia = 0; ia < 4; ia++)
            #pragma unroll
            for (int ib = 0; ib < 4; ib++)
                acc[ia][ib] = fmaf(a[ia], b[ib], acc[ia][ib]);
    }
    #pragma unroll
    for (int ia = 0; ia < 4; ia++) {
        float4 o = make_float4(acc[ia][0], acc[ia][1], acc[ia][2], acc[ia][3]);
        *(float4*)&out[((size_t)(i0 + 4 * ty + ia) * NHEAD + h) * HDIM + e0 + 4 * tx] = o;
    }
}

// ---------------------------------------------------------------------------
// Kernel C v2: single pass over pos_emb (453 MB), LDS-traffic-minimized.
// Block i computes for all 24 rows (12 qp heads + 12 kp heads) and all j:
//   A1 [h*S*S + i*S + j] = sum_e pe[i,j,e] * qp[i,h,e]
//   P2T[h*S*S + i*S + j] = sum_e pe[i,j,e] * kp[i,h,e]
// 256 threads / 4 waves. Wave w: rg=w>>1 selects qp/kp rows, es=w&1 selects
// e-half of each 32-e chunk. Lane owns 6 j's: {4L..4L+3, 256+2L, 257+2L}.
// W values are wave-uniform -> scalar (s_load) path, NOT staged in LDS.
// P chunk transposed to LDS [e][j] with float2 (adjacent-j) writes.
// ---------------------------------------------------------------------------
__global__ __launch_bounds__(256)
void scores_pos(const float* __restrict__ pe, const float* __restrict__ qp,
                const float* __restrict__ kp,
                float* __restrict__ A1, float* __restrict__ P2T)
{
    __shared__ float lds[32 * 388];   // Ps chunk [e][388]; reused as Acc[24][392]
    const int i    = blockIdx.x;
    const int tid  = threadIdx.x;
    const int lane = tid & 63;
    const int wave = tid >> 6;
    const int rgu = __builtin_amdgcn_readfirstlane(wave >> 1);
    const int esu = __builtin_amdgcn_readfirstlane(wave & 1);

    const float* pebase = pe + (size_t)i * SEQ * HDIM;
    const float* wb = (rgu ? kp : qp) + (size_t)i * NHEAD * HDIM;

    const int wr  = tid >> 3;       // 0..31 (j pair base)
    const int wec = tid & 7;        // 0..7  (float4 within 32-e chunk)

    float acc[12][6] = {};

    for (int c = 0; c < 24; c++) {
        const int e0 = c * 32;
        __syncthreads();   // protect LDS from previous chunk's readers
        #pragma unroll
        for (int rnd = 0; rnd < 6; rnd++) {
            const int jb = rnd * 64 + wr * 2;
            float4 g0 = *(const float4*)&pebase[(size_t)jb * HDIM + e0 + wec * 4];
            float4 g1 = *(const float4*)&pebase[(size_t)(jb + 1) * HDIM + e0 + wec * 4];
            *(float2*)&lds[(wec * 4 + 0) * 388 + jb] = make_float2(g0.x, g1.x);
            *(float2*)&lds[(wec * 4 + 1) * 388 + jb] = make_float2(g0.y, g1.y);
            *(float2*)&lds[(wec * 4 + 2) * 388 + jb] = make_float2(g0.z, g1.z);
            *(float2*)&lds[(wec * 4 + 3) * 388 + jb] = make_float2(g0.w, g1.w);
        }
        __syncthreads();
        const float* wc = wb + e0 + esu * 16;   // wave-uniform -> scalar loads
        #pragma unroll 4
        for (int ee = 0; ee < 16; ee++) {
            const int ei = esu * 16 + ee;
            float4 p4 = *(const float4*)&lds[ei * 388 + lane * 4];
            float2 p2 = *(const float2*)&lds[ei * 388 + 256 + lane * 2];
            #pragma unroll
            for (int r = 0; r < 12; r++) {
                const float w = wc[r * HDIM + ee];
                acc[r][0] = fmaf(w, p4.x, acc[r][0]);
                acc[r][1] = fmaf(w, p4.y, acc[r][1]);
                acc[r][2] = fmaf(w, p4.z, acc[r][2]);
                acc[r][3] = fmaf(w, p4.w, acc[r][3]);
                acc[r][4] = fmaf(w, p2.x, acc[r][4]);
                acc[r][5] = fmaf(w, p2.y, acc[r][5]);
            }
        }
    }

    // Combine the two e-half partials through LDS (Acc[24][392] aliases Ps).
    __syncthreads();
    if (esu == 1) {
        #pragma unroll
        for (int r = 0; r < 12; r++) {
            const int row = rgu * 12 + r;
            *(float4*)&lds[row * 392 + lane * 4] =
                make_float4(acc[r][0], acc[r][1], acc[r][2], acc[r][3]);
            *(float2*)&lds[row * 392 + 256 + lane * 2] =
                make_float2(acc[r][4], acc[r][5]);
        }
    }
    __syncthreads();
    if (esu == 0) {
        #pragma unroll
        for (int r = 0; r < 12; r++) {
            const int row = rgu * 12 + r;
            float4 o4 = *(const float4*)&lds[row * 392 + lane * 4];
            float2 o2 = *(const float2*)&lds[row * 392 + 256 + lane * 2];
            o4.x += acc[r][0]; o4.y += acc[r][1]; o4.z += acc[r][2]; o4.w += acc[r][3];
            o2.x += acc[r][4]; o2.y += acc[r][5];
            *(float4*)&lds[row * 392 + lane * 4] = o4;
            *(float2*)&lds[row * 392 + 256 + lane * 2] = o2;
        }
    }
    __syncthreads();

    // Coalesced store phase: 24 rows x 384 cols from LDS to global.
    for (int t = tid; t < 24 * 96; t += 256) {
        const int row = t / 96;
        const int c4  = (t % 96) * 4;
        float4 o = *(const float4*)&lds[row * 392 + c4];
        float* dst = (row < 12)
            ? &A1[((size_t)row * SEQ + i) * SEQ + c4]
            : &P2T[((size_t)(row - 12) * SEQ + i) * SEQ + c4];
        *(float4*)dst = o;
    }
}

// ---------------------------------------------------------------------------
// Kernel D: per-(i,h) block (384 threads, thread = j):
//   scores[j] = (c2c + A1[h,i,j] + P2T[h,j,i] + qb + kb[j]) / 8 + mask[j]
//   softmax over j, then out[i, h*64+d] = sum_j p_j v[j, h*64+d] / sum
// ---------------------------------------------------------------------------
__global__ __launch_bounds__(384)
void attn_out(const float* __restrict__ A1, const float* __restrict__ P2T,
              const float* __restrict__ q, const float* __restrict__ k,
              const float* __restrict__ v,
              const float* __restrict__ bpk, const float* __restrict__ bpq,
              const float* __restrict__ mask, float* __restrict__ out)
{
    const int i = blockIdx.x, h = blockIdx.y;
    const int tid = threadIdx.x;   // = j
    __shared__ float q_s[64], bk_s[64], bq_s[64];
    __shared__ float p_s[SEQ];
    __shared__ float redm[6], reds[6], redv[6 * 64];

    if (tid < 64)       q_s[tid]        = q[(size_t)i * HDIM + h * 64 + tid];
    else if (tid < 128) bk_s[tid - 64]  = bpk[h * 64 + tid - 64];
    else if (tid < 192) bq_s[tid - 128] = bpq[h * 64 + tid - 128];
    __syncthreads();

    const float* kr = k + (size_t)tid * HDIM + h * 64;
    float c2c = 0.f, kb = 0.f;
    #pragma unroll
    for (int dd = 0; dd < 16; dd++) {
        float4 k4 = *(const float4*)(kr + 4 * dd);
        c2c = fmaf(q_s[4 * dd + 0], k4.x, c2c);
        c2c = fmaf(q_s[4 * dd + 1], k4.y, c2c);
        c2c = fmaf(q_s[4 * dd + 2], k4.z, c2c);
        c2c = fmaf(q_s[4 * dd + 3], k4.w, c2c);
        kb  = fmaf(bq_s[4 * dd + 0], k4.x, kb);
        kb  = fmaf(bq_s[4 * dd + 1], k4.y, kb);
        kb  = fmaf(bq_s[4 * dd + 2], k4.z, kb);
        kb  = fmaf(bq_s[4 * dd + 3], k4.w, kb);
    }
    float qb = 0.f;
    #pragma unroll 8
    for (int d = 0; d < 64; d++) qb = fmaf(q_s[d], bk_s[d], qb);

    float sc = (A1[((size_t)h * SEQ + i) * SEQ + tid] +
                P2T[((size_t)h * SEQ + tid) * SEQ + i] +
                c2c + kb + qb) * 0.125f + mask[tid];

    const int lane = tid & 63, w = tid >> 6;
    float m = sc;
    #pragma unroll
    for (int o = 32; o; o >>= 1) m = fmaxf(m, __shfl_xor(m, o));
    if (lane == 0) redm[w] = m;
    __syncthreads();
    m = redm[0];
    #pragma unroll
    for (int t = 1; t < 6; t++) m = fmaxf(m, redm[t]);

    float p = __expf(sc - m);
    float sum = p;
    #pragma unroll
    for (int o = 32; o; o >>= 1) sum += __shfl_xor(sum, o);
    if (lane == 0) reds[w] = sum;
    p_s[tid] = p;
    __syncthreads();
    const float SUM = reds[0] + reds[1] + reds[2] + reds[3] + reds[4] + reds[5];

    float accv = 0.f;
    const float* vbase = v + h * 64 + lane;
    const int j0 = w * 64;
    #pragma unroll 8
    for (int jj = 0; jj < 64; jj++)
        accv = fmaf(p_s[j0 + jj], vbase[(size_t)(j0 + jj) * HDIM], accv);
    redv[w * 64 + lane] = accv;
    __syncthreads();
    if (tid < 64) {
        float o = redv[tid] + redv[64 + tid] + redv[128 + tid] +
                  redv[192 + tid] + redv[256 + tid] + redv[320 + tid];
        out[(size_t)i * HDIM + h * 64 + tid] = o / SUM;
    }
}

// ---------------------------------------------------------------------------
extern "C" void kernel_launch(void* const* d_in, const int* in_sizes, int n_in,
                              void* d_out, int out_size, void* d_ws, size_t ws_size,
                              hipStream_t stream)
{
    const float* hs   = (const float*)d_in[0];
    const float* mask = (const float*)d_in[1];
    const float* pe   = (const float*)d_in[2];
    const float* Wq   = (const float*)d_in[3];
    const float* bq   = (const float*)d_in[4];
    const float* Wk   = (const float*)d_in[5];
    const float* bk   = (const float*)d_in[6];
    const float* Wv   = (const float*)d_in[7];
    const float* bv   = (const float*)d_in[8];
    const float* Wpk  = (const float*)d_in[9];
    const float* bpk  = (const float*)d_in[10];
    const float* Wpq  = (const float*)d_in[11];
    const float* bpq  = (const float*)d_in[12];

    float* ws = (float*)d_ws;
    const size_t SZ_QKV = (size_t)SEQ * HDIM;            // 294912
    const size_t SZ_QP  = (size_t)SEQ * NHEAD * HDIM;    // 3538944
    const size_t SZ_SC  = (size_t)NHEAD * SEQ * SEQ;     // 1769472
    float* q   = ws;
    float* k   = q  + SZ_QKV;
    float* v   = k  + SZ_QKV;
    float* qp  = v  + SZ_QKV;
    float* kp  = qp + SZ_QP;
    float* A1  = kp + SZ_QP;
    float* P2T = A1 + SZ_SC;

    qkv_gemm<<<dim3(6, 12, 3), 256, 0, stream>>>(hs, Wq, bq, Wk, bk, Wv, bv, q, k, v);
    pos_proj<<<dim3(6, 12, 24), 256, 0, stream>>>(q, k, Wpk, Wpq, qp, kp);
    scores_pos<<<dim3(SEQ), 256, 0, stream>>>(pe, qp, kp, A1, P2T);
    attn_out<<<dim3(SEQ, NHEAD), 384, 0, stream>>>(A1, P2T, q, k, v, bpk, bpq, mask,
                                                   (float*)d_out);
}

// Round 3
// 845.143 us; speedup vs baseline: 1.0191x; 1.0155x over previous
//
#include <hip/hip_runtime.h>
#include <math.h>

// Problem constants
#define SEQ 384
#define HDIM 768
#define NHEAD 12
#define DHEAD 64

// ---------------------------------------------------------------------------
// Kernel A: fused QKV projection.  C = X @ W + b for W in {Wq,Wk,Wv}
// v3: X staged in LDS (k-panels of 128, transposed), W streamed from L2
// (wave-uniform row + 16-lane-broadcast 256B reads) -> halves LDS-pipe load.
// grid (6 mtiles, 12 ntiles, 3 matrices), block 256, tile 64x64.
// ---------------------------------------------------------------------------
__global__ __launch_bounds__(256)
void qkv_gemm(const float* __restrict__ X,
              const float* __restrict__ Wq, const float* __restrict__ bq,
              const float* __restrict__ Wk, const float* __restrict__ bk,
              const float* __restrict__ Wv, const float* __restrict__ bv,
              float* __restrict__ q, float* __restrict__ k, float* __restrict__ v)
{
    __shared__ float Xs[128 * 68];   // [k][m], padded stride 68
    const int z = blockIdx.z;
    const float* W    = (z == 0) ? Wq : (z == 1) ? Wk : Wv;
    const float* bias = (z == 0) ? bq : (z == 1) ? bk : bv;
    float* out        = (z == 0) ? q  : (z == 1) ? k  : v;

    const int m0 = blockIdx.x * 64;
    const int n0 = blockIdx.y * 64;
    const int tid = threadIdx.x;
    const int ty = tid / 16, tx = tid % 16;

    const int lm = tid >> 2;          // 0..63 (m row)
    const int lc = (tid & 3) * 4;     // 0,4,8,12 (k sub-col)

    float acc[4][4] = {};

    for (int k0 = 0; k0 < HDIM; k0 += 128) {
        float4 xa[8];
        #pragma unroll
        for (int it = 0; it < 8; it++)
            xa[it] = *(const float4*)&X[(size_t)(m0 + lm) * HDIM + k0 + it * 16 + lc];
        __syncthreads();
        #pragma unroll
        for (int it = 0; it < 8; it++) {
            const int kk = it * 16 + lc;
            Xs[(kk + 0) * 68 + lm] = xa[it].x;
            Xs[(kk + 1) * 68 + lm] = xa[it].y;
            Xs[(kk + 2) * 68 + lm] = xa[it].z;
            Xs[(kk + 3) * 68 + lm] = xa[it].w;
        }
        __syncthreads();
        const float* Wp = &W[(size_t)k0 * HDIM + n0 + 4 * tx];
        #pragma unroll 8
        for (int kk = 0; kk < 128; kk++) {
            float4 b4 = *(const float4*)&Wp[(size_t)kk * HDIM];
            float4 a4 = *(const float4*)&Xs[kk * 68 + 4 * ty];
            float a[4] = {a4.x, a4.y, a4.z, a4.w};
            float b[4] = {b4.x, b4.y, b4.z, b4.w};
            #pragma unroll
            for (int ia = 0; ia < 4; ia++)
                #pragma unroll
                for (int ib = 0; ib < 4; ib++)
                    acc[ia][ib] = fmaf(a[ia], b[ib], acc[ia][ib]);
        }
    }
    float4 bv4 = *(const float4*)&bias[n0 + 4 * tx];
    #pragma unroll
    for (int ia = 0; ia < 4; ia++) {
        float4 o;
        o.x = acc[ia][0] + bv4.x; o.y = acc[ia][1] + bv4.y;
        o.z = acc[ia][2] + bv4.z; o.w = acc[ia][3] + bv4.w;
        *(float4*)&out[(size_t)(m0 + 4 * ty + ia) * HDIM + n0 + 4 * tx] = o;
    }
}

// ---------------------------------------------------------------------------
// Kernel B: positional projections (unchanged).
//   qp[i,h,e] = sum_d q[i, h*64+d] * Wpk[e*768 + h*64 + d]
//   kp[j,h,e] = sum_d k[j, h*64+d] * Wpq[e*768 + h*64 + d]
// output layout: qp[(i*12 + h)*768 + e]
// ---------------------------------------------------------------------------
__global__ __launch_bounds__(256)
void pos_proj(const float* __restrict__ q, const float* __restrict__ k,
              const float* __restrict__ Wpk, const float* __restrict__ Wpq,
              float* __restrict__ qp, float* __restrict__ kp)
{
    __shared__ float As[64][68];   // [d][i]
    __shared__ float Bs[64][68];   // [d][e]
    const int h = blockIdx.z % NHEAD;
    const int s = blockIdx.z / NHEAD;
    const float* Asrc = s ? k   : q;
    const float* Wsrc = s ? Wpq : Wpk;
    float* out        = s ? kp  : qp;

    const int i0 = blockIdx.x * 64, e0 = blockIdx.y * 64;
    const int tid = threadIdx.x;
    const int dg = tid % 16, row = tid / 16;

    #pragma unroll
    for (int r = 0; r < 4; r++) {
        const int rr = r * 16 + row;
        float4 a4 = *(const float4*)&Asrc[(size_t)(i0 + rr) * HDIM + h * 64 + dg * 4];
        float4 b4 = *(const float4*)&Wsrc[(size_t)(e0 + rr) * HDIM + h * 64 + dg * 4];
        As[dg * 4 + 0][rr] = a4.x; As[dg * 4 + 1][rr] = a4.y;
        As[dg * 4 + 2][rr] = a4.z; As[dg * 4 + 3][rr] = a4.w;
        Bs[dg * 4 + 0][rr] = b4.x; Bs[dg * 4 + 1][rr] = b4.y;
        Bs[dg * 4 + 2][rr] = b4.z; Bs[dg * 4 + 3][rr] = b4.w;
    }
    __syncthreads();

    const int ty = tid / 16, tx = tid % 16;
    float acc[4][4] = {};
    #pragma unroll 4
    for (int d = 0; d < 64; d++) {
        float4 a4 = *(const float4*)&As[d][4 * ty];
        float4 b4 = *(const float4*)&Bs[d][4 * tx];
        float a[4] = {a4.x, a4.y, a4.z, a4.w};
        float b[4] = {b4.x, b4.y, b4.z, b4.w};
        #pragma unroll
        for (int ia = 0; ia < 4; ia++)
            #pragma unroll
            for (int ib = 0; ib < 4; ib++)
                acc[ia][ib] = fmaf(a[ia], b[ib], acc[ia][ib]);
    }
    #pragma unroll
    for (int ia = 0; ia < 4; ia++) {
        float4 o = make_float4(acc[ia][0], acc[ia][1], acc[ia][2], acc[ia][3]);
        *(float4*)&out[((size_t)(i0 + 4 * ty + ia) * NHEAD + h) * HDIM + e0 + 4 * tx] = o;
    }
}

// ---------------------------------------------------------------------------
// Kernel C v3: single pass over pos_emb (453 MB), j-split for load balance.
// Block (i, jh) handles j in [jh*192, jh*192+192):
//   A1 [h*S*S + i*S + j] = sum_e pe[i,j,e] * qp[i,h,e]
//   P2T[h*S*S + i*S + j] = sum_e pe[i,j,e] * kp[i,h,e]
// grid (384,2) = 768 blocks = exactly 3/CU (vs v2's 1.5 avg with 2x tail).
// 256 threads / 4 waves; wave: rg=w>>1 (qp|kp), es=w&1 (e-half of chunk).
// Lane owns 3 j's: {2L, 2L+1, 128+L}. W via wave-uniform scalar loads.
// Staging: all 6 global loads issued to registers before LDS writes.
// ---------------------------------------------------------------------------
__global__ __launch_bounds__(256)
void scores_pos(const float* __restrict__ pe, const float* __restrict__ qp,
                const float* __restrict__ kp,
                float* __restrict__ A1, float* __restrict__ P2T)
{
    __shared__ float lds[32 * 200];   // Ps chunk [e][192 +pad8]; reused Acc[24][200]
    const int i    = blockIdx.x;
    const int jh   = blockIdx.y;      // 0,1
    const int tid  = threadIdx.x;
    const int lane = tid & 63;
    const int wave = tid >> 6;
    const int rgu = __builtin_amdgcn_readfirstlane(wave >> 1);
    const int esu = __builtin_amdgcn_readfirstlane(wave & 1);

    const float* pebase = pe + ((size_t)i * SEQ + jh * 192) * HDIM;
    const float* wb = (rgu ? kp : qp) + (size_t)i * NHEAD * HDIM;

    const int wr  = tid >> 3;       // 0..31 (local j pair base /2)
    const int wec = tid & 7;        // 0..7  (float4 within 32-e chunk)

    float acc[12][3] = {};

    for (int c = 0; c < 24; c++) {
        const int e0 = c * 32;
        float4 g[6];
        #pragma unroll
        for (int rnd = 0; rnd < 3; rnd++) {
            const int jb = rnd * 64 + wr * 2;
            g[2 * rnd + 0] = *(const float4*)&pebase[(size_t)jb * HDIM + e0 + wec * 4];
            g[2 * rnd + 1] = *(const float4*)&pebase[(size_t)(jb + 1) * HDIM + e0 + wec * 4];
        }
        __syncthreads();   // protect LDS from previous chunk's readers
        #pragma unroll
        for (int rnd = 0; rnd < 3; rnd++) {
            const int jb = rnd * 64 + wr * 2;
            const float4 g0 = g[2 * rnd], g1 = g[2 * rnd + 1];
            *(float2*)&lds[(wec * 4 + 0) * 200 + jb] = make_float2(g0.x, g1.x);
            *(float2*)&lds[(wec * 4 + 1) * 200 + jb] = make_float2(g0.y, g1.y);
            *(float2*)&lds[(wec * 4 + 2) * 200 + jb] = make_float2(g0.z, g1.z);
            *(float2*)&lds[(wec * 4 + 3) * 200 + jb] = make_float2(g0.w, g1.w);
        }
        __syncthreads();
        const float* wc = wb + e0 + esu * 16;   // wave-uniform -> scalar loads
        #pragma unroll 4
        for (int ee = 0; ee < 16; ee++) {
            const int ei = esu * 16 + ee;
            float2 p2 = *(const float2*)&lds[ei * 200 + 2 * lane];
            float  p1 = lds[ei * 200 + 128 + lane];
            #pragma unroll
            for (int r = 0; r < 12; r++) {
                const float w = wc[r * HDIM + ee];
                acc[r][0] = fmaf(w, p2.x, acc[r][0]);
                acc[r][1] = fmaf(w, p2.y, acc[r][1]);
                acc[r][2] = fmaf(w, p1,   acc[r][2]);
            }
        }
    }

    // Combine the two e-half partials through LDS (Acc[24][200] aliases Ps).
    __syncthreads();
    if (esu == 1) {
        #pragma unroll
        for (int r = 0; r < 12; r++) {
            const int row = rgu * 12 + r;
            *(float2*)&lds[row * 200 + 2 * lane] = make_float2(acc[r][0], acc[r][1]);
            lds[row * 200 + 128 + lane] = acc[r][2];
        }
    }
    __syncthreads();
    if (esu == 0) {
        #pragma unroll
        for (int r = 0; r < 12; r++) {
            const int row = rgu * 12 + r;
            float2 o2 = *(const float2*)&lds[row * 200 + 2 * lane];
            float  o1 = lds[row * 200 + 128 + lane];
            o2.x += acc[r][0]; o2.y += acc[r][1]; o1 += acc[r][2];
            *(float2*)&lds[row * 200 + 2 * lane] = o2;
            lds[row * 200 + 128 + lane] = o1;
        }
    }
    __syncthreads();

    // Coalesced store: 24 rows x 192 cols from LDS to global.
    for (int t = tid; t < 24 * 48; t += 256) {
        const int row = t / 48;
        const int c4  = (t % 48) * 4;
        float4 o = *(const float4*)&lds[row * 200 + c4];
        float* dst = (row < 12)
            ? &A1[((size_t)row * SEQ + i) * SEQ + jh * 192 + c4]
            : &P2T[((size_t)(row - 12) * SEQ + i) * SEQ + jh * 192 + c4];
        *(float4*)dst = o;
    }
}

// ---------------------------------------------------------------------------
// Kernel D v2: per-(i,h) block (384 threads, thread = j for score phase):
//   scores[j] = (c2c + A1[h,i,j] + P2T[h,j,i] + qb + kb[j]) / 8 + mask[j]
//   softmax over j; PV phase re-mapped: wave w covers j in [64w,64w+64),
//   lane = 16*jsub + dq loads v[j0+4*jj+jsub][4dq..4dq+3] as float4
//   (4 j x 256 B coalesced per instr, 16 instrs/wave vs 64 scalar).
// ---------------------------------------------------------------------------
__global__ __launch_bounds__(384)
void attn_out(const float* __restrict__ A1, const float* __restrict__ P2T,
              const float* __restrict__ q, const float* __restrict__ k,
              const float* __restrict__ v,
              const float* __restrict__ bpk, const float* __restrict__ bpq,
              const float* __restrict__ mask, float* __restrict__ out)
{
    const int i = blockIdx.x, h = blockIdx.y;
    const int tid = threadIdx.x;   // = j
    __shared__ float q_s[64], bk_s[64], bq_s[64];
    __shared__ float p_s[SEQ];
    __shared__ float redm[6], reds[6];
    __shared__ float redvf[24 * 64];

    if (tid < 64)       q_s[tid]        = q[(size_t)i * HDIM + h * 64 + tid];
    else if (tid < 128) bk_s[tid - 64]  = bpk[h * 64 + tid - 64];
    else if (tid < 192) bq_s[tid - 128] = bpq[h * 64 + tid - 128];
    __syncthreads();

    const float* kr = k + (size_t)tid * HDIM + h * 64;
    float c2c = 0.f, kb = 0.f;
    #pragma unroll
    for (int dd = 0; dd < 16; dd++) {
        float4 k4 = *(const float4*)(kr + 4 * dd);
        c2c = fmaf(q_s[4 * dd + 0], k4.x, c2c);
        c2c = fmaf(q_s[4 * dd + 1], k4.y, c2c);
        c2c = fmaf(q_s[4 * dd + 2], k4.z, c2c);
        c2c = fmaf(q_s[4 * dd + 3], k4.w, c2c);
        kb  = fmaf(bq_s[4 * dd + 0], k4.x, kb);
        kb  = fmaf(bq_s[4 * dd + 1], k4.y, kb);
        kb  = fmaf(bq_s[4 * dd + 2], k4.z, kb);
        kb  = fmaf(bq_s[4 * dd + 3], k4.w, kb);
    }
    float qb = 0.f;
    #pragma unroll 8
    for (int d = 0; d < 64; d++) qb = fmaf(q_s[d], bk_s[d], qb);

    float sc = (A1[((size_t)h * SEQ + i) * SEQ + tid] +
                P2T[((size_t)h * SEQ + tid) * SEQ + i] +
                c2c + kb + qb) * 0.125f + mask[tid];

    const int lane = tid & 63, w = tid >> 6;
    float m = sc;
    #pragma unroll
    for (int o = 32; o; o >>= 1) m = fmaxf(m, __shfl_xor(m, o));
    if (lane == 0) redm[w] = m;
    __syncthreads();
    m = redm[0];
    #pragma unroll
    for (int t = 1; t < 6; t++) m = fmaxf(m, redm[t]);

    float p = __expf(sc - m);
    float sum = p;
    #pragma unroll
    for (int o = 32; o; o >>= 1) sum += __shfl_xor(sum, o);
    if (lane == 0) reds[w] = sum;
    p_s[tid] = p;
    __syncthreads();
    const float SUM = reds[0] + reds[1] + reds[2] + reds[3] + reds[4] + reds[5];

    // PV phase: vectorized over d.
    const int dq = lane & 15, jsub = lane >> 4;
    const int j0 = w * 64;
    float4 av = make_float4(0.f, 0.f, 0.f, 0.f);
    #pragma unroll 8
    for (int jj = 0; jj < 16; jj++) {
        const int j = j0 + jj * 4 + jsub;
        float4 v4 = *(const float4*)&v[(size_t)j * HDIM + h * 64 + dq * 4];
        const float pj = p_s[j];
        av.x = fmaf(pj, v4.x, av.x); av.y = fmaf(pj, v4.y, av.y);
        av.z = fmaf(pj, v4.z, av.z); av.w = fmaf(pj, v4.w, av.w);
    }
    *(float4*)&redvf[(w * 4 + jsub) * 64 + dq * 4] = av;
    __syncthreads();
    if (tid < 64) {
        float o = 0.f;
        #pragma unroll
        for (int r = 0; r < 24; r++) o += redvf[r * 64 + tid];
        out[(size_t)i * HDIM + h * 64 + tid] = o / SUM;
    }
}

// ---------------------------------------------------------------------------
extern "C" void kernel_launch(void* const* d_in, const int* in_sizes, int n_in,
                              void* d_out, int out_size, void* d_ws, size_t ws_size,
                              hipStream_t stream)
{
    const float* hs   = (const float*)d_in[0];
    const float* mask = (const float*)d_in[1];
    const float* pe   = (const float*)d_in[2];
    const float* Wq   = (const float*)d_in[3];
    const float* bq   = (const float*)d_in[4];
    const float* Wk   = (const float*)d_in[5];
    const float* bk   = (const float*)d_in[6];
    const float* Wv   = (const float*)d_in[7];
    const float* bv   = (const float*)d_in[8];
    const float* Wpk  = (const float*)d_in[9];
    const float* bpk  = (const float*)d_in[10];
    const float* Wpq  = (const float*)d_in[11];
    const float* bpq  = (const float*)d_in[12];

    float* ws = (float*)d_ws;
    const size_t SZ_QKV = (size_t)SEQ * HDIM;            // 294912
    const size_t SZ_QP  = (size_t)SEQ * NHEAD * HDIM;    // 3538944
    const size_t SZ_SC  = (size_t)NHEAD * SEQ * SEQ;     // 1769472
    float* q   = ws;
    float* k   = q  + SZ_QKV;
    float* v   = k  + SZ_QKV;
    float* qp  = v  + SZ_QKV;
    float* kp  = qp + SZ_QP;
    float* A1  = kp + SZ_QP;
    float* P2T = A1 + SZ_SC;

    qkv_gemm<<<dim3(6, 12, 3), 256, 0, stream>>>(hs, Wq, bq, Wk, bk, Wv, bv, q, k, v);
    pos_proj<<<dim3(6, 12, 24), 256, 0, stream>>>(q, k, Wpk, Wpq, qp, kp);
    scores_pos<<<dim3(SEQ, 2), 256, 0, stream>>>(pe, qp, kp, A1, P2T);
    attn_out<<<dim3(SEQ, NHEAD), 384, 0, stream>>>(A1, P2T, q, k, v, bpk, bpq, mask,
                                                   (float*)d_out);
}